// Round 3
// baseline (1702.552 us; speedup 1.0000x reference)
//
#include <hip/hip_runtime.h>
#include <hip/hip_bf16.h>

// Problem constants
#define HIDDEN 4096
#define NHEADS 32
#define HDIM   128
#define BSZ    2
#define QLEN   2048
#define NKT    128   // K-steps: 4096 / 32

typedef __attribute__((ext_vector_type(4))) float          f32x4;
typedef __attribute__((ext_vector_type(8))) __bf16         bf16x8;
typedef __attribute__((ext_vector_type(8))) unsigned short u16x8;
typedef __attribute__((ext_vector_type(4))) unsigned int   u32x4;

__device__ __forceinline__ unsigned short f2bf(float x) {
  __hip_bfloat16 h = __float2bfloat16(x);
  return __builtin_bit_cast(unsigned short, h);
}
__device__ __forceinline__ float bf2f(unsigned short u) {
  return __builtin_bit_cast(float, (unsigned)u << 16);
}
__device__ __forceinline__ f32x4 mfma16(u16x8 a, u16x8 b, f32x4 c) {
  return __builtin_amdgcn_mfma_f32_16x16x32_bf16(
      __builtin_bit_cast(bf16x8, a), __builtin_bit_cast(bf16x8, b), c, 0, 0, 0);
}
// async global->LDS, 16B per lane; LDS dest = wave-uniform base + lane*16
__device__ __forceinline__ void gload_lds16(const void* g, void* l) {
  __builtin_amdgcn_global_load_lds(
      (const __attribute__((address_space(1))) unsigned int*)g,
      (__attribute__((address_space(3))) unsigned int*)l, 16, 0, 0);
}

// ---------------------------------------------------------------------------
// Kernel 1: RoPE cos/sin table.  tab[s*128 + j] = cos(s*invfreq_j), +64 = sin
// ---------------------------------------------------------------------------
__global__ void rope_table(float* __restrict__ tab) {
  const int s = blockIdx.x;
  const int j = threadIdx.x;  // 0..63
  float inv = powf(10000.0f, -(float)j / 64.0f);
  float ang = (float)s * inv;
  float sv, cv;
  sincosf(ang, &sv, &cv);
  tab[s * 128 + j] = cv;
  tab[s * 128 + 64 + j] = sv;
}

// ---------------------------------------------------------------------------
// Kernel 2: split fp32 matrix into bf16 hi/lo, packed in GEMM LDS-image order.
// Pack layout: [row_tile rt][kt][r 0..127][128 B row: hi(64B)|lo(64B), each row
// XOR-swizzled by ((r&7)<<4)].  One thread per 16B granule -> perfectly
// coalesced writes; reads are row-contiguous float4 pairs.
// Per-matrix pack size: rows * 2*HIDDEN bf16 elements (hi+lo planes).
// ---------------------------------------------------------------------------
__global__ void split_pack(const float* __restrict__ src,
                           unsigned short* __restrict__ dst) {
  const int gid = blockIdx.x * 256 + threadIdx.x;  // granule id
  const int t = gid >> 10;          // tile = rt*NKT + kt
  const int g = gid & 1023;
  const int r = g >> 3;
  const int b = (g & 7) << 4;                 // physical byte in 128B row
  const int b0 = b ^ ((r & 7) << 4);          // logical byte (involution)
  const int part = b0 >> 6;                   // 0 = hi, 1 = lo
  const int kc0 = (b0 & 63) >> 1;             // element offset in k-strip
  const int m = ((t >> 7) << 7) + r;          // global row
  const int k = ((t & (NKT - 1)) << 5) + kc0; // global col
  const float4* p = (const float4*)(src + (size_t)m * HIDDEN + k);
  float4 a = p[0], c = p[1];
  float x[8] = {a.x, a.y, a.z, a.w, c.x, c.y, c.z, c.w};
  u16x8 v;
#pragma unroll
  for (int i = 0; i < 8; ++i) {
    unsigned short h = f2bf(x[i]);
    unsigned short l = f2bf(x[i] - bf2f(h));
    v[i] = part ? l : h;
  }
  *(u16x8*)(dst + (size_t)gid * 8) = v;
}

// ---------------------------------------------------------------------------
// Kernel 3: QKV GEMM on pre-packed bf16 hi/lo.  C[m,n] = sum_k A[m,k]*W[n,k],
// 3-product split (hi*hi + hi*lo + lo*hi) for fp32-class accuracy.
// 128x128 tile, BK=32, 4 waves (2x2), global_load_lds staging, m97 2-barrier
// loop, swizzled conflict-free ds_read_b128.  Epilogue -> bf16 Q/K/V
// [b][h][s][d].
// ---------------------------------------------------------------------------
__global__ __launch_bounds__(256, 2) void qkv_gemm(
    const unsigned short* __restrict__ Apk, const unsigned short* __restrict__ Wpk,
    unsigned short* __restrict__ Qb, unsigned short* __restrict__ Kb,
    unsigned short* __restrict__ Vb) {
  __shared__ __align__(16) char ldsA[2][16384];
  __shared__ __align__(16) char ldsB[2][16384];
  const int bm = blockIdx.x;   // 32
  const int bn = blockIdx.y;   // 96
  const int tid = threadIdx.x, lane = tid & 63, wid = tid >> 6;
  const int wr = wid >> 1, wc = wid & 1;
  const int lr = lane & 15, lg = lane >> 4;
  const char* Abase = (const char*)Apk + (size_t)bm * NKT * 16384;
  const char* Bbase = (const char*)Wpk + (size_t)bn * NKT * 16384;

  f32x4 acc[4][4] = {};

  auto stage = [&](int buf, int kt) {
    const char* as = Abase + (size_t)kt * 16384;
    const char* bs = Bbase + (size_t)kt * 16384;
#pragma unroll
    for (int j = 0; j < 4; ++j) {
      const int c0 = wid * 64 + j * 256;  // wave-uniform chunk base
      gload_lds16(as + (size_t)(c0 + lane) * 16, &ldsA[buf][c0 * 16]);
      gload_lds16(bs + (size_t)(c0 + lane) * 16, &ldsB[buf][c0 * 16]);
    }
  };

  stage(0, 0);
#pragma unroll 1
  for (int kt = 0; kt < NKT; ++kt) {
    const int buf = kt & 1;
    __syncthreads();  // drains vmcnt: stage(buf) complete; prev compute done
    if (kt + 1 < NKT) stage(buf ^ 1, kt + 1);
    u16x8 ah[4], al[4], bh[4], bl[4];
#pragma unroll
    for (int mi = 0; mi < 4; ++mi) {
      const int r = wr * 64 + mi * 16 + lr, sw = (r & 7) << 4;
      ah[mi] = *(const u16x8*)&ldsA[buf][r * 128 + ((lg << 4) ^ sw)];
      al[mi] = *(const u16x8*)&ldsA[buf][r * 128 + ((64 + (lg << 4)) ^ sw)];
    }
#pragma unroll
    for (int ni = 0; ni < 4; ++ni) {
      const int r = wc * 64 + ni * 16 + lr, sw = (r & 7) << 4;
      bh[ni] = *(const u16x8*)&ldsB[buf][r * 128 + ((lg << 4) ^ sw)];
      bl[ni] = *(const u16x8*)&ldsB[buf][r * 128 + ((64 + (lg << 4)) ^ sw)];
    }
#pragma unroll
    for (int mi = 0; mi < 4; ++mi)
#pragma unroll
      for (int ni = 0; ni < 4; ++ni) {
        acc[mi][ni] = mfma16(ah[mi], bh[ni], acc[mi][ni]);  // hi*hi
        acc[mi][ni] = mfma16(ah[mi], bl[ni], acc[mi][ni]);  // hi*lo
        acc[mi][ni] = mfma16(al[mi], bh[ni], acc[mi][ni]);  // lo*hi
      }
  }

  // Epilogue: n-block (128 cols) is entirely one (q/k/v, head) pair.
  const int which = bn >> 5, hh = bn & 31;
  unsigned short* dst = (which == 0) ? Qb : ((which == 1) ? Kb : Vb);
#pragma unroll
  for (int mi = 0; mi < 4; ++mi)
#pragma unroll
    for (int r = 0; r < 4; ++r) {
      int m = bm * 128 + wr * 64 + mi * 16 + (lg << 2) + r;
      int b = m >> 11, s = m & (QLEN - 1);
      unsigned short* orow =
          dst + ((size_t)((b << 5) + hh) * QLEN + s) * HDIM + wc * 64;
#pragma unroll
      for (int ni = 0; ni < 4; ++ni) orow[ni * 16 + lr] = f2bf(acc[mi][ni][r]);
    }
}

// ---------------------------------------------------------------------------
// Kernel 4: RoPE applied in place to Q and K (bf16), vectorized x8.
// ---------------------------------------------------------------------------
__global__ void rope_apply(unsigned short* __restrict__ Qb,
                           unsigned short* __restrict__ Kb,
                           const float* __restrict__ tab) {
  const int idx = blockIdx.x * 256 + threadIdx.x;  // 1,048,576 total
  const int jg = (idx & 7) << 3;                   // 0,8,...,56
  const int s = (idx >> 3) & (QLEN - 1);
  const int bh = idx >> 14;
  const size_t base = ((size_t)bh * QLEN + s) * HDIM;
  const float* tc = tab + s * 128 + jg;
  const float* ts = tab + s * 128 + 64 + jg;
  u16x8 q1 = *(const u16x8*)(Qb + base + jg);
  u16x8 q2 = *(const u16x8*)(Qb + base + 64 + jg);
  u16x8 k1 = *(const u16x8*)(Kb + base + jg);
  u16x8 k2 = *(const u16x8*)(Kb + base + 64 + jg);
  u16x8 a1, a2, b1, b2;
#pragma unroll
  for (int i = 0; i < 8; ++i) {
    float c = tc[i], sn = ts[i];
    a1[i] = f2bf(bf2f(q1[i]) * c - bf2f(q2[i]) * sn);
    a2[i] = f2bf(bf2f(q2[i]) * c + bf2f(q1[i]) * sn);
    b1[i] = f2bf(bf2f(k1[i]) * c - bf2f(k2[i]) * sn);
    b2[i] = f2bf(bf2f(k2[i]) * c + bf2f(k1[i]) * sn);
  }
  *(u16x8*)(Qb + base + jg) = a1;
  *(u16x8*)(Qb + base + 64 + jg) = a2;
  *(u16x8*)(Kb + base + jg) = b1;
  *(u16x8*)(Kb + base + 64 + jg) = b2;
}

// ---------------------------------------------------------------------------
// Kernel 5: transpose V [bh][s][d] -> Vt [bh][d][s]  (64x64 tiles via LDS)
// ---------------------------------------------------------------------------
__global__ void vtrans(const unsigned short* __restrict__ Vb,
                       unsigned short* __restrict__ Vt) {
  __shared__ unsigned short t[64][72];
  const int s0 = blockIdx.x * 64, d0 = blockIdx.y * 64, bh = blockIdx.z;
  const int tid = threadIdx.x;
  const int r = tid >> 2, c4 = (tid & 3) << 4;
  const unsigned short* src = Vb + ((size_t)(bh * QLEN) + s0 + r) * HDIM + d0 + c4;
  *(u32x4*)&t[r][c4] = *(const u32x4*)src;
  *(u32x4*)&t[r][c4 + 8] = *(const u32x4*)(src + 8);
  __syncthreads();
  unsigned short* dst = Vt + ((size_t)(bh * HDIM) + d0 + r) * QLEN + s0 + c4;
#pragma unroll
  for (int i = 0; i < 16; ++i) dst[i] = t[c4 + i][r];
}

// ---------------------------------------------------------------------------
// Kernel 6: flash attention.  Block: 4 waves x 32 q-rows = 128 rows, one (b,h).
// KV tiles of 64, K and Vt staged in LDS with XOR swizzle (G4 fix for D=128).
// Online softmax in f32, P staged per-wave in LDS as bf16 for the PV MFMA.
// ---------------------------------------------------------------------------
__global__ __launch_bounds__(256, 2) void attn(
    const unsigned short* __restrict__ Qb, const unsigned short* __restrict__ Kb,
    const unsigned short* __restrict__ Vt, float* __restrict__ out) {
  __shared__ unsigned short Kl[64 * 128];   // swizzled rows
  __shared__ unsigned short Vl[128 * 64];   // Vt tile, swizzled rows
  __shared__ unsigned short Pl[4][32 * 72]; // per-wave P staging
  const int bh = blockIdx.y;
  const int qb0 = blockIdx.x << 7;
  const int tid = threadIdx.x, lane = tid & 63, w = tid >> 6;
  const int qw = qb0 + w * 32;
  const int lr = lane & 15, lg = lane >> 4, lk = lg << 3;

  const unsigned short* Qbase = Qb + (size_t)bh * QLEN * HDIM;
  u16x8 qf[2][4];
#pragma unroll
  for (int mi = 0; mi < 2; ++mi)
#pragma unroll
    for (int kc = 0; kc < 4; ++kc)
      qf[mi][kc] = *(const u16x8*)(Qbase + (size_t)(qw + mi * 16 + lr) * HDIM +
                                   kc * 32 + lk);

  f32x4 o[2][8];
  float mrun[2][4], lrun[2][4];
#pragma unroll
  for (int mi = 0; mi < 2; ++mi) {
#pragma unroll
    for (int dn = 0; dn < 8; ++dn) o[mi][dn] = (f32x4)0.0f;
#pragma unroll
    for (int r = 0; r < 4; ++r) { mrun[mi][r] = -3.0e38f; lrun[mi][r] = 0.0f; }
  }

  const int ntiles = (qb0 >> 6) + 2;  // causal: tiles up to block diagonal
  const int krow = tid >> 2, kcg = (tid & 3) << 5;
  const int vd = tid >> 1, vcg = (tid & 1) << 5;
  const unsigned short* Ksrc0 = Kb + (size_t)(bh * QLEN + krow) * HDIM + kcg;
  const unsigned short* Vsrc0 = Vt + (size_t)(bh * HDIM + vd) * QLEN + vcg;
  char* kdst = (char*)Kl + krow * 256;
  char* vdst = (char*)Vl + vd * 128;
  const int ksw = (krow & 7) << 4, vsw = (vd & 7) << 4;
  const float KC = 0.1275254f;  // (1/sqrt(128)) * log2(e)

  for (int t = 0; t < ntiles; ++t) {
    const int kb = t << 6;
    __syncthreads();  // previous tile fully consumed before overwrite
#pragma unroll
    for (int i = 0; i < 4; ++i) {
      *(u32x4*)(kdst + (((kcg + i * 8) << 1) ^ ksw)) =
          *(const u32x4*)(Ksrc0 + (size_t)kb * HDIM + i * 8);
      *(u32x4*)(vdst + (((vcg + i * 8) << 1) ^ vsw)) =
          *(const u32x4*)(Vsrc0 + kb + i * 8);
    }
    __syncthreads();
    if (kb > qw + 31) continue;  // fully-masked tile for this wave (uniform)

    // ---- Q @ K^T ----
    f32x4 sc[2][4];
#pragma unroll
    for (int mi = 0; mi < 2; ++mi)
#pragma unroll
      for (int kn = 0; kn < 4; ++kn) sc[mi][kn] = (f32x4)0.0f;
#pragma unroll
    for (int kc = 0; kc < 4; ++kc) {
      u16x8 kf[4];
#pragma unroll
      for (int kn = 0; kn < 4; ++kn) {
        int row = kn * 16 + lr;
        kf[kn] = *(const u16x8*)((char*)Kl + row * 256 +
                                 (((kc << 6) + (lg << 4)) ^ ((row & 7) << 4)));
      }
#pragma unroll
      for (int mi = 0; mi < 2; ++mi)
#pragma unroll
        for (int kn = 0; kn < 4; ++kn)
          sc[mi][kn] = mfma16(qf[mi][kc], kf[kn], sc[mi][kn]);
    }
    // ---- causal mask ----
    if (kb + 63 > qw) {
#pragma unroll
      for (int mi = 0; mi < 2; ++mi)
#pragma unroll
        for (int kn = 0; kn < 4; ++kn)
#pragma unroll
          for (int r = 0; r < 4; ++r) {
            int qrow = qw + mi * 16 + (lg << 2) + r;
            int key = kb + kn * 16 + lr;
            if (key > qrow) sc[mi][kn][r] = -3.0e38f;
          }
    }
    // ---- online softmax (f32, reduce over 16-lane groups) ----
#pragma unroll
    for (int mi = 0; mi < 2; ++mi)
#pragma unroll
      for (int r = 0; r < 4; ++r) {
        float mx = fmaxf(fmaxf(sc[mi][0][r], sc[mi][1][r]),
                         fmaxf(sc[mi][2][r], sc[mi][3][r]));
        mx = fmaxf(mx, __shfl_xor(mx, 1, 64));
        mx = fmaxf(mx, __shfl_xor(mx, 2, 64));
        mx = fmaxf(mx, __shfl_xor(mx, 4, 64));
        mx = fmaxf(mx, __shfl_xor(mx, 8, 64));
        float mold = mrun[mi][r];
        float mnew = fmaxf(mold, mx);
        float corr = exp2f((mold - mnew) * KC);
        mrun[mi][r] = mnew;
        float rs = 0.0f;
#pragma unroll
        for (int kn = 0; kn < 4; ++kn) {
          float p = exp2f((sc[mi][kn][r] - mnew) * KC);
          sc[mi][kn][r] = p;
          rs += p;
        }
        rs += __shfl_xor(rs, 1, 64);
        rs += __shfl_xor(rs, 2, 64);
        rs += __shfl_xor(rs, 4, 64);
        rs += __shfl_xor(rs, 8, 64);
        lrun[mi][r] = lrun[mi][r] * corr + rs;
#pragma unroll
        for (int dn = 0; dn < 8; ++dn) o[mi][dn][r] *= corr;
      }
    // ---- P -> LDS (bf16), then PV ----
    unsigned short* pw = Pl[w];
#pragma unroll
    for (int mi = 0; mi < 2; ++mi)
#pragma unroll
      for (int kn = 0; kn < 4; ++kn)
#pragma unroll
        for (int r = 0; r < 4; ++r)
          pw[(mi * 16 + (lg << 2) + r) * 72 + kn * 16 + lr] =
              f2bf(sc[mi][kn][r]);
    asm volatile("s_waitcnt lgkmcnt(0)" ::: "memory");
#pragma unroll
    for (int kc = 0; kc < 2; ++kc) {
      u16x8 pf[2];
#pragma unroll
      for (int mi = 0; mi < 2; ++mi)
        pf[mi] = *(const u16x8*)(pw + (mi * 16 + lr) * 72 + (kc << 5) + lk);
#pragma unroll
      for (int dn = 0; dn < 8; ++dn) {
        int d = dn * 16 + lr;
        u16x8 vf = *(const u16x8*)((char*)Vl + d * 128 +
                                   (((kc << 6) + (lg << 4)) ^ ((d & 7) << 4)));
#pragma unroll
        for (int mi = 0; mi < 2; ++mi) o[mi][dn] = mfma16(pf[mi], vf, o[mi][dn]);
      }
    }
  }
  // ---- epilogue: O / l, write f32 out[b][s][h*128+d] ----
  const int b = bh >> 5, hh = bh & 31;
#pragma unroll
  for (int mi = 0; mi < 2; ++mi)
#pragma unroll
    for (int r = 0; r < 4; ++r) {
      int s = qw + mi * 16 + (lg << 2) + r;
      float inv = 1.0f / lrun[mi][r];
      float* orow = out + ((size_t)(b * QLEN + s) << 12) + hh * 128;
#pragma unroll
      for (int dn = 0; dn < 8; ++dn) orow[dn * 16 + lr] = o[mi][dn][r] * inv;
    }
}

// ---------------------------------------------------------------------------
extern "C" void kernel_launch(void* const* d_in, const int* in_sizes, int n_in,
                              void* d_out, int out_size, void* d_ws,
                              size_t ws_size, hipStream_t stream) {
  (void)in_sizes; (void)n_in; (void)out_size; (void)ws_size;
  const float* hidden = (const float*)d_in[0];
  const float* W = (const float*)d_in[1];
  // d_in[2] (causal mask) and d_in[3] (position_ids = arange) are implicit.
  float* out = (float*)d_out;

  const size_t NELT = (size_t)BSZ * NHEADS * QLEN * HDIM;  // 16,777,216
  unsigned short* Qb = (unsigned short*)d_ws;
  unsigned short* Kb = Qb + NELT;
  unsigned short* Vb = Kb + NELT;
  unsigned short* Vt = Vb + NELT;
  float* tab = (float*)(Vt + NELT);                        // 2048*128 f32
  unsigned short* Apk = (unsigned short*)((char*)tab + (size_t)QLEN * 128 * 4);
  // A pack: 4096 rows x 2*HIDDEN bf16 (hi+lo) = 64 MB = 2*HIDDEN*HIDDEN shorts
  unsigned short* Wpk = Apk + (size_t)2 * HIDDEN * HIDDEN;
  // W pack: 12288 rows x 2*HIDDEN bf16 = 192 MB.  Total ws use ~385 MB.

  hipLaunchKernelGGL(rope_table, dim3(QLEN), dim3(64), 0, stream, tab);
  hipLaunchKernelGGL(split_pack, dim3(16384), dim3(256), 0, stream,
                     hidden, Apk);   // 32 row-tiles
  hipLaunchKernelGGL(split_pack, dim3(49152), dim3(256), 0, stream,
                     W, Wpk);        // 96 row-tiles
  hipLaunchKernelGGL(qkv_gemm, dim3(32, 96), dim3(256), 0, stream,
                     Apk, Wpk, Qb, Kb, Vb);
  hipLaunchKernelGGL(rope_apply, dim3(4096), dim3(256), 0, stream,
                     Qb, Kb, tab);
  hipLaunchKernelGGL(vtrans, dim3(QLEN / 64, HDIM / 64, BSZ * NHEADS),
                     dim3(256), 0, stream, Vb, Vt);
  hipLaunchKernelGGL(attn, dim3(QLEN / 128, BSZ * NHEADS), dim3(256), 0,
                     stream, Qb, Kb, Vt, out);
}

// Round 4
// 1062.799 us; speedup vs baseline: 1.6020x; 1.6020x over previous
//
#include <hip/hip_runtime.h>
#include <hip/hip_bf16.h>

// Problem constants
#define HIDDEN 4096
#define NHEADS 32
#define HDIM   128
#define BSZ    2
#define QLEN   2048
#define NKT    128   // K-steps: 4096 / 32

typedef __attribute__((ext_vector_type(4))) float          f32x4;
typedef __attribute__((ext_vector_type(8))) __bf16         bf16x8;
typedef __attribute__((ext_vector_type(8))) unsigned short u16x8;
typedef __attribute__((ext_vector_type(4))) unsigned int   u32x4;

__device__ __forceinline__ unsigned short f2bf(float x) {
  __hip_bfloat16 h = __float2bfloat16(x);
  return __builtin_bit_cast(unsigned short, h);
}
__device__ __forceinline__ float bf2f(unsigned short u) {
  return __builtin_bit_cast(float, (unsigned)u << 16);
}
__device__ __forceinline__ f32x4 mfma16(u16x8 a, u16x8 b, f32x4 c) {
  return __builtin_amdgcn_mfma_f32_16x16x32_bf16(
      __builtin_bit_cast(bf16x8, a), __builtin_bit_cast(bf16x8, b), c, 0, 0, 0);
}
// async global->LDS, 16B per lane; LDS dest = wave-uniform base + lane*16
__device__ __forceinline__ void gload_lds16(const void* g, void* l) {
  __builtin_amdgcn_global_load_lds(
      (const __attribute__((address_space(1))) unsigned int*)g,
      (__attribute__((address_space(3))) unsigned int*)l, 16, 0, 0);
}

// ---------------------------------------------------------------------------
// Kernel 1: RoPE cos/sin table.  tab[s*128 + j] = cos(s*invfreq_j), +64 = sin
// ---------------------------------------------------------------------------
__global__ void rope_table(float* __restrict__ tab) {
  const int s = blockIdx.x;
  const int j = threadIdx.x;  // 0..63
  float inv = powf(10000.0f, -(float)j / 64.0f);
  float ang = (float)s * inv;
  float sv, cv;
  sincosf(ang, &sv, &cv);
  tab[s * 128 + j] = cv;
  tab[s * 128 + 64 + j] = sv;
}

// ---------------------------------------------------------------------------
// Kernel 2: cast fp32 matrix to bf16, packed in GEMM LDS-image order.
// Pack layout: [row_tile rt][kt][8 KB tile].  Tile = 128 rows x 32 k bf16,
// row = 64 B; physical granule offset = (r*64 + q*16) ^ ((r&7)<<4)  (bijective
// XOR swizzle, conflict-free for the 16-row fragment ds_read_b128).
// One thread per logical 16B granule (8 bf16 = 8 f32 of one row's k-strip).
// ---------------------------------------------------------------------------
__global__ void split_pack(const float* __restrict__ src,
                           unsigned short* __restrict__ dst) {
  const int gid = blockIdx.x * 256 + threadIdx.x;  // logical granule id
  const int t = gid >> 9;           // tile = rt*NKT + kt   (512 granules/tile)
  const int g = gid & 511;
  const int r = g >> 2;             // row 0..127
  const int q = g & 3;              // 16B k-granule 0..3
  const int m = ((t >> 7) << 7) + r;            // global row
  const int k = ((t & (NKT - 1)) << 5) + q * 8; // global col
  const float4* p = (const float4*)(src + (size_t)m * HIDDEN + k);
  float4 a = p[0], c = p[1];
  float x[8] = {a.x, a.y, a.z, a.w, c.x, c.y, c.z, c.w};
  u16x8 v;
#pragma unroll
  for (int i = 0; i < 8; ++i) v[i] = f2bf(x[i]);
  const int phys = (r * 64 + q * 16) ^ ((r & 7) << 4);
  *(u16x8*)((char*)dst + (size_t)t * 8192 + phys) = v;
}

// ---------------------------------------------------------------------------
// Kernel 3: QKV GEMM on packed bf16.  C[m,n] = sum_k A[m,k]*W[n,k].
// 128x128 tile, BK=32, 4 waves (2x2), global_load_lds staging, m97 2-barrier
// loop, swizzled conflict-free ds_read_b128.  16 MFMA : 8 ds_read : 4 gload
// per K-step.  LDS 32 KB -> 4 blocks/CU.  Epilogue -> bf16 Q/K/V [b][h][s][d].
// ---------------------------------------------------------------------------
__global__ __launch_bounds__(256, 4) void qkv_gemm(
    const unsigned short* __restrict__ Apk, const unsigned short* __restrict__ Wpk,
    unsigned short* __restrict__ Qb, unsigned short* __restrict__ Kb,
    unsigned short* __restrict__ Vb) {
  __shared__ __align__(16) char ldsA[2][8192];
  __shared__ __align__(16) char ldsB[2][8192];
  const int bm = blockIdx.x;   // 32
  const int bn = blockIdx.y;   // 96
  const int tid = threadIdx.x, lane = tid & 63, wid = tid >> 6;
  const int wr = wid >> 1, wc = wid & 1;
  const int lr = lane & 15, lg = lane >> 4;   // frag row / k-quarter
  const char* Abase = (const char*)Apk + (size_t)bm * NKT * 8192;
  const char* Bbase = (const char*)Wpk + (size_t)bn * NKT * 8192;

  f32x4 acc[4][4] = {};

  auto stage = [&](int buf, int kt) {
    const char* as = Abase + (size_t)kt * 8192;
    const char* bs = Bbase + (size_t)kt * 8192;
#pragma unroll
    for (int j = 0; j < 2; ++j) {
      const int c0 = wid * 64 + j * 256;  // wave-uniform granule base (0..511)
      gload_lds16(as + (size_t)(c0 + lane) * 16, &ldsA[buf][c0 * 16]);
      gload_lds16(bs + (size_t)(c0 + lane) * 16, &ldsB[buf][c0 * 16]);
    }
  };

  stage(0, 0);
#pragma unroll 1
  for (int kt = 0; kt < NKT; ++kt) {
    const int buf = kt & 1;
    __syncthreads();  // drains vmcnt: stage(buf) complete; prev compute done
    if (kt + 1 < NKT) stage(buf ^ 1, kt + 1);
    u16x8 af[4], bf[4];
#pragma unroll
    for (int mi = 0; mi < 4; ++mi) {
      const int r = wr * 64 + mi * 16 + lr;
      af[mi] = *(const u16x8*)&ldsA[buf][(r * 64 + (lg << 4)) ^ ((r & 7) << 4)];
    }
#pragma unroll
    for (int ni = 0; ni < 4; ++ni) {
      const int r = wc * 64 + ni * 16 + lr;
      bf[ni] = *(const u16x8*)&ldsB[buf][(r * 64 + (lg << 4)) ^ ((r & 7) << 4)];
    }
#pragma unroll
    for (int mi = 0; mi < 4; ++mi)
#pragma unroll
      for (int ni = 0; ni < 4; ++ni)
        acc[mi][ni] = mfma16(af[mi], bf[ni], acc[mi][ni]);
  }

  // Epilogue: n-block (128 cols) is entirely one (q/k/v, head) pair.
  const int which = bn >> 5, hh = bn & 31;
  unsigned short* dst = (which == 0) ? Qb : ((which == 1) ? Kb : Vb);
#pragma unroll
  for (int mi = 0; mi < 4; ++mi)
#pragma unroll
    for (int r = 0; r < 4; ++r) {
      int m = bm * 128 + wr * 64 + mi * 16 + (lg << 2) + r;
      int b = m >> 11, s = m & (QLEN - 1);
      unsigned short* orow =
          dst + ((size_t)((b << 5) + hh) * QLEN + s) * HDIM + wc * 64;
#pragma unroll
      for (int ni = 0; ni < 4; ++ni) orow[ni * 16 + lr] = f2bf(acc[mi][ni][r]);
    }
}

// ---------------------------------------------------------------------------
// Kernel 4: RoPE applied in place to Q and K (bf16), vectorized x8.
// ---------------------------------------------------------------------------
__global__ void rope_apply(unsigned short* __restrict__ Qb,
                           unsigned short* __restrict__ Kb,
                           const float* __restrict__ tab) {
  const int idx = blockIdx.x * 256 + threadIdx.x;  // 1,048,576 total
  const int jg = (idx & 7) << 3;                   // 0,8,...,56
  const int s = (idx >> 3) & (QLEN - 1);
  const int bh = idx >> 14;
  const size_t base = ((size_t)bh * QLEN + s) * HDIM;
  const float* tc = tab + s * 128 + jg;
  const float* ts = tab + s * 128 + 64 + jg;
  u16x8 q1 = *(const u16x8*)(Qb + base + jg);
  u16x8 q2 = *(const u16x8*)(Qb + base + 64 + jg);
  u16x8 k1 = *(const u16x8*)(Kb + base + jg);
  u16x8 k2 = *(const u16x8*)(Kb + base + 64 + jg);
  u16x8 a1, a2, b1, b2;
#pragma unroll
  for (int i = 0; i < 8; ++i) {
    float c = tc[i], sn = ts[i];
    a1[i] = f2bf(bf2f(q1[i]) * c - bf2f(q2[i]) * sn);
    a2[i] = f2bf(bf2f(q2[i]) * c + bf2f(q1[i]) * sn);
    b1[i] = f2bf(bf2f(k1[i]) * c - bf2f(k2[i]) * sn);
    b2[i] = f2bf(bf2f(k2[i]) * c + bf2f(k1[i]) * sn);
  }
  *(u16x8*)(Qb + base + jg) = a1;
  *(u16x8*)(Qb + base + 64 + jg) = a2;
  *(u16x8*)(Kb + base + jg) = b1;
  *(u16x8*)(Kb + base + 64 + jg) = b2;
}

// ---------------------------------------------------------------------------
// Kernel 5: transpose V [bh][s][d] -> Vt [bh][d][s]  (64x64 tiles via LDS)
// ---------------------------------------------------------------------------
__global__ void vtrans(const unsigned short* __restrict__ Vb,
                       unsigned short* __restrict__ Vt) {
  __shared__ unsigned short t[64][72];
  const int s0 = blockIdx.x * 64, d0 = blockIdx.y * 64, bh = blockIdx.z;
  const int tid = threadIdx.x;
  const int r = tid >> 2, c4 = (tid & 3) << 4;
  const unsigned short* src = Vb + ((size_t)(bh * QLEN) + s0 + r) * HDIM + d0 + c4;
  *(u32x4*)&t[r][c4] = *(const u32x4*)src;
  *(u32x4*)&t[r][c4 + 8] = *(const u32x4*)(src + 8);
  __syncthreads();
  unsigned short* dst = Vt + ((size_t)(bh * HDIM) + d0 + r) * QLEN + s0 + c4;
#pragma unroll
  for (int i = 0; i < 16; ++i) dst[i] = t[c4 + i][r];
}

// ---------------------------------------------------------------------------
// Kernel 6: flash attention.  Block: 4 waves x 32 q-rows = 128 rows, one (b,h).
// KV tiles of 64, K and Vt staged in LDS with XOR swizzle (G4 fix for D=128).
// Online softmax in f32, P staged per-wave in LDS as bf16 for the PV MFMA.
// ---------------------------------------------------------------------------
__global__ __launch_bounds__(256, 2) void attn(
    const unsigned short* __restrict__ Qb, const unsigned short* __restrict__ Kb,
    const unsigned short* __restrict__ Vt, float* __restrict__ out) {
  __shared__ unsigned short Kl[64 * 128];   // swizzled rows
  __shared__ unsigned short Vl[128 * 64];   // Vt tile, swizzled rows
  __shared__ unsigned short Pl[4][32 * 72]; // per-wave P staging
  const int bh = blockIdx.y;
  const int qb0 = blockIdx.x << 7;
  const int tid = threadIdx.x, lane = tid & 63, w = tid >> 6;
  const int qw = qb0 + w * 32;
  const int lr = lane & 15, lg = lane >> 4, lk = lg << 3;

  const unsigned short* Qbase = Qb + (size_t)bh * QLEN * HDIM;
  u16x8 qf[2][4];
#pragma unroll
  for (int mi = 0; mi < 2; ++mi)
#pragma unroll
    for (int kc = 0; kc < 4; ++kc)
      qf[mi][kc] = *(const u16x8*)(Qbase + (size_t)(qw + mi * 16 + lr) * HDIM +
                                   kc * 32 + lk);

  f32x4 o[2][8];
  float mrun[2][4], lrun[2][4];
#pragma unroll
  for (int mi = 0; mi < 2; ++mi) {
#pragma unroll
    for (int dn = 0; dn < 8; ++dn) o[mi][dn] = (f32x4)0.0f;
#pragma unroll
    for (int r = 0; r < 4; ++r) { mrun[mi][r] = -3.0e38f; lrun[mi][r] = 0.0f; }
  }

  const int ntiles = (qb0 >> 6) + 2;  // causal: tiles up to block diagonal
  const int krow = tid >> 2, kcg = (tid & 3) << 5;
  const int vd = tid >> 1, vcg = (tid & 1) << 5;
  const unsigned short* Ksrc0 = Kb + (size_t)(bh * QLEN + krow) * HDIM + kcg;
  const unsigned short* Vsrc0 = Vt + (size_t)(bh * HDIM + vd) * QLEN + vcg;
  char* kdst = (char*)Kl + krow * 256;
  char* vdst = (char*)Vl + vd * 128;
  const int ksw = (krow & 7) << 4, vsw = (vd & 7) << 4;
  const float KC = 0.1275254f;  // (1/sqrt(128)) * log2(e)

  for (int t = 0; t < ntiles; ++t) {
    const int kb = t << 6;
    __syncthreads();  // previous tile fully consumed before overwrite
#pragma unroll
    for (int i = 0; i < 4; ++i) {
      *(u32x4*)(kdst + (((kcg + i * 8) << 1) ^ ksw)) =
          *(const u32x4*)(Ksrc0 + (size_t)kb * HDIM + i * 8);
      *(u32x4*)(vdst + (((vcg + i * 8) << 1) ^ vsw)) =
          *(const u32x4*)(Vsrc0 + kb + i * 8);
    }
    __syncthreads();
    if (kb > qw + 31) continue;  // fully-masked tile for this wave (uniform)

    // ---- Q @ K^T ----
    f32x4 sc[2][4];
#pragma unroll
    for (int mi = 0; mi < 2; ++mi)
#pragma unroll
      for (int kn = 0; kn < 4; ++kn) sc[mi][kn] = (f32x4)0.0f;
#pragma unroll
    for (int kc = 0; kc < 4; ++kc) {
      u16x8 kf[4];
#pragma unroll
      for (int kn = 0; kn < 4; ++kn) {
        int row = kn * 16 + lr;
        kf[kn] = *(const u16x8*)((char*)Kl + row * 256 +
                                 (((kc << 6) + (lg << 4)) ^ ((row & 7) << 4)));
      }
#pragma unroll
      for (int mi = 0; mi < 2; ++mi)
#pragma unroll
        for (int kn = 0; kn < 4; ++kn)
          sc[mi][kn] = mfma16(qf[mi][kc], kf[kn], sc[mi][kn]);
    }
    // ---- causal mask ----
    if (kb + 63 > qw) {
#pragma unroll
      for (int mi = 0; mi < 2; ++mi)
#pragma unroll
        for (int kn = 0; kn < 4; ++kn)
#pragma unroll
          for (int r = 0; r < 4; ++r) {
            int qrow = qw + mi * 16 + (lg << 2) + r;
            int key = kb + kn * 16 + lr;
            if (key > qrow) sc[mi][kn][r] = -3.0e38f;
          }
    }
    // ---- online softmax (f32, reduce over 16-lane groups) ----
#pragma unroll
    for (int mi = 0; mi < 2; ++mi)
#pragma unroll
      for (int r = 0; r < 4; ++r) {
        float mx = fmaxf(fmaxf(sc[mi][0][r], sc[mi][1][r]),
                         fmaxf(sc[mi][2][r], sc[mi][3][r]));
        mx = fmaxf(mx, __shfl_xor(mx, 1, 64));
        mx = fmaxf(mx, __shfl_xor(mx, 2, 64));
        mx = fmaxf(mx, __shfl_xor(mx, 4, 64));
        mx = fmaxf(mx, __shfl_xor(mx, 8, 64));
        float mold = mrun[mi][r];
        float mnew = fmaxf(mold, mx);
        float corr = exp2f((mold - mnew) * KC);
        mrun[mi][r] = mnew;
        float rs = 0.0f;
#pragma unroll
        for (int kn = 0; kn < 4; ++kn) {
          float p = exp2f((sc[mi][kn][r] - mnew) * KC);
          sc[mi][kn][r] = p;
          rs += p;
        }
        rs += __shfl_xor(rs, 1, 64);
        rs += __shfl_xor(rs, 2, 64);
        rs += __shfl_xor(rs, 4, 64);
        rs += __shfl_xor(rs, 8, 64);
        lrun[mi][r] = lrun[mi][r] * corr + rs;
#pragma unroll
        for (int dn = 0; dn < 8; ++dn) o[mi][dn][r] *= corr;
      }
    // ---- P -> LDS (bf16), then PV ----
    unsigned short* pw = Pl[w];
#pragma unroll
    for (int mi = 0; mi < 2; ++mi)
#pragma unroll
      for (int kn = 0; kn < 4; ++kn)
#pragma unroll
        for (int r = 0; r < 4; ++r)
          pw[(mi * 16 + (lg << 2) + r) * 72 + kn * 16 + lr] =
              f2bf(sc[mi][kn][r]);
    asm volatile("s_waitcnt lgkmcnt(0)" ::: "memory");
#pragma unroll
    for (int kc = 0; kc < 2; ++kc) {
      u16x8 pf[2];
#pragma unroll
      for (int mi = 0; mi < 2; ++mi)
        pf[mi] = *(const u16x8*)(pw + (mi * 16 + lr) * 72 + (kc << 5) + lk);
#pragma unroll
      for (int dn = 0; dn < 8; ++dn) {
        int d = dn * 16 + lr;
        u16x8 vf = *(const u16x8*)((char*)Vl + d * 128 +
                                   (((kc << 6) + (lg << 4)) ^ ((d & 7) << 4)));
#pragma unroll
        for (int mi = 0; mi < 2; ++mi) o[mi][dn] = mfma16(pf[mi], vf, o[mi][dn]);
      }
    }
  }
  // ---- epilogue: O / l, write f32 out[b][s][h*128+d] ----
  const int b = bh >> 5, hh = bh & 31;
#pragma unroll
  for (int mi = 0; mi < 2; ++mi)
#pragma unroll
    for (int r = 0; r < 4; ++r) {
      int s = qw + mi * 16 + (lg << 2) + r;
      float inv = 1.0f / lrun[mi][r];
      float* orow = out + ((size_t)(b * QLEN + s) << 12) + hh * 128;
#pragma unroll
      for (int dn = 0; dn < 8; ++dn) orow[dn * 16 + lr] = o[mi][dn][r] * inv;
    }
}

// ---------------------------------------------------------------------------
extern "C" void kernel_launch(void* const* d_in, const int* in_sizes, int n_in,
                              void* d_out, int out_size, void* d_ws,
                              size_t ws_size, hipStream_t stream) {
  (void)in_sizes; (void)n_in; (void)out_size; (void)ws_size;
  const float* hidden = (const float*)d_in[0];
  const float* W = (const float*)d_in[1];
  // d_in[2] (causal mask) and d_in[3] (position_ids = arange) are implicit.
  float* out = (float*)d_out;

  const size_t NELT = (size_t)BSZ * NHEADS * QLEN * HDIM;  // 16,777,216
  unsigned short* Qb = (unsigned short*)d_ws;
  unsigned short* Kb = Qb + NELT;
  unsigned short* Vb = Kb + NELT;
  unsigned short* Vt = Vb + NELT;
  float* tab = (float*)(Vt + NELT);                        // 2048*128 f32
  unsigned short* Apk = (unsigned short*)((char*)tab + (size_t)QLEN * 128 * 4);
  // A pack: 4096 rows x HIDDEN bf16 = 32 MB = HIDDEN*HIDDEN shorts
  unsigned short* Wpk = Apk + (size_t)HIDDEN * HIDDEN;
  // W pack: 12288 rows x HIDDEN bf16 = 96 MB.  Total ws use ~265 MB.

  hipLaunchKernelGGL(rope_table, dim3(QLEN), dim3(64), 0, stream, tab);
  hipLaunchKernelGGL(split_pack, dim3(8192), dim3(256), 0, stream,
                     hidden, Apk);   // 4096 rows
  hipLaunchKernelGGL(split_pack, dim3(24576), dim3(256), 0, stream,
                     W, Wpk);        // 12288 rows
  hipLaunchKernelGGL(qkv_gemm, dim3(32, 96), dim3(256), 0, stream,
                     Apk, Wpk, Qb, Kb, Vb);
  hipLaunchKernelGGL(rope_apply, dim3(4096), dim3(256), 0, stream,
                     Qb, Kb, tab);
  hipLaunchKernelGGL(vtrans, dim3(QLEN / 64, HDIM / 64, BSZ * NHEADS),
                     dim3(256), 0, stream, Vb, Vt);
  hipLaunchKernelGGL(attn, dim3(QLEN / 128, BSZ * NHEADS), dim3(256), 0,
                     stream, Qb, Kb, Vt, out);
}